// Round 14
// baseline (236.871 us; speedup 1.0000x reference)
//
#include <hip/hip_runtime.h>
#include <hip/hip_bf16.h>

// Problem constants
constexpr int kB   = 2;
constexpr int kS   = 2048;
constexpr int kD   = 1024;
constexpr int kH   = 16;
constexpr int kDh  = 64;
constexpr int kBS  = kB * kS;          // 4096 rows

typedef __attribute__((ext_vector_type(8))) short short8;   // 8 bf16 = 4 VGPRs
typedef __attribute__((ext_vector_type(4))) float floatx4;  // MFMA acc 16x16
typedef __attribute__((ext_vector_type(16))) float floatx16; // MFMA acc 32x32

__device__ inline unsigned short f2b(float f) {
    __hip_bfloat16 h = __float2bfloat16(f);
    return *reinterpret_cast<unsigned short*>(&h);
}

__device__ inline float b2f(unsigned short u) {
    union { unsigned u; float f; } cv;
    cv.u = (unsigned)u << 16;
    return cv.f;
}

__device__ inline floatx4 mfma16(short8 a, short8 b, floatx4 c) {
    return __builtin_amdgcn_mfma_f32_16x16x32_bf16(a, b, c, 0, 0, 0);
}

__device__ inline floatx16 mfma32(short8 a, short8 b, floatx16 c) {
    return __builtin_amdgcn_mfma_f32_32x32x16_bf16(a, b, c, 0, 0, 0);
}

// truncating pack of two f32 -> one u32 of 2 bf16 (lo = a, hi = b).
// Truncating is part of the round-3 verified arithmetic — do not change
// (absmax 0.03125 depends on reproducing it bit-exactly).
__device__ inline unsigned packbf(float a, float b) {
    union { float f; unsigned u; } x, y;
    x.f = a; y.f = b;
    return (x.u >> 16) | (y.u & 0xffff0000u);
}

// async global->LDS, 16B per lane; LDS dest = wave-uniform base + lane*16
__device__ inline void gload16(const unsigned short* g, unsigned short* l) {
    __builtin_amdgcn_global_load_lds(
        (const __attribute__((address_space(1))) void*)g,
        (__attribute__((address_space(3))) void*)l, 16, 0, 0);
}

// ---------------------------------------------------------------------------
// K0: fp32 -> bf16 conversion of x (4M elems) and the 4 weights (4 x 1M elems)
// 2048 blocks + 4-step grid-stride (guideline 11).
// ---------------------------------------------------------------------------
__global__ void convert_kernel(const float* __restrict__ x,
                               const float* __restrict__ wq, const float* __restrict__ wk,
                               const float* __restrict__ wv, const float* __restrict__ wo,
                               unsigned short* __restrict__ xb, unsigned short* __restrict__ wb) {
#pragma unroll
    for (int it = 0; it < 4; it++) {
        int gid = blockIdx.x * blockDim.x + threadIdx.x + it * (2048 * 256);
        long i4 = (long)gid * 4;
        const float* src;
        unsigned short* dst;
        long off;
        if (i4 < (long)kBS * kD) {
            src = x; dst = xb; off = i4;
        } else {
            long w = i4 - (long)kBS * kD;
            int sel = (int)(w >> 20);
            off = w & 1048575;
            src = (sel == 0) ? wq : (sel == 1) ? wk : (sel == 2) ? wv : wo;
            dst = wb + (long)sel * 1048576;
        }
        float4 v = *(const float4*)(src + off);
        ushort4 o;
        o.x = f2b(v.x); o.y = f2b(v.y); o.z = f2b(v.z); o.w = f2b(v.w);
        *(ushort4*)(dst + off) = o;
    }
}

// ---------------------------------------------------------------------------
// K1: NT GEMM  C[M,N] = A[M,K] @ B[N,K]^T   (bf16 in, fp32 accum)
// Round 14: issue-early double-buffer at BK=32. The old loop staged then
// IMMEDIATELY drained (stage; barrier; compute; barrier — zero DMA/compute
// overlap, the known ~20% m97 drain stall). New: two 16KB buffers (rows of
// 32 elems, 4x16B chunks, chunk p of row r holds logical chunk p^(r&3));
// stage next BK=32 BEFORE computing current; ONE barrier per iter. LDS
// still 32 KB -> 3 blocks/CU preserved, 768 blocks = one generation.
// BIT-EXACT: the old h=0/h=1 k-halves become two successive iters with
// identical operand values in identical order -> same per-output MFMA chain.
// MODE 0: bf16 C; z==0 (Q) scaled by 0.125*log2(e) (exp2 domain).
// ---------------------------------------------------------------------------
template <int MODE>
__launch_bounds__(256, 3)
__global__ void gemm_nt(const unsigned short* __restrict__ A,
                        const unsigned short* __restrict__ Bw,
                        void* __restrict__ Cout,
                        const float* __restrict__ resid,
                        int M, int N, int K) {
    // [buf][0]=A rows, [buf][1]=B rows; each [128][32] bf16 = 8 KB.
    __shared__ __align__(16) unsigned short Sh[2][2][128 * 32];

    const int z  = blockIdx.z;
    const unsigned short* Bp = Bw + (size_t)z * N * K;
    const int m0 = blockIdx.y * 128, n0 = blockIdx.x * 128;
    const int tid  = threadIdx.x;
    const int lane = tid & 63, wv = tid >> 6;
    const int wm = wv >> 1, wn = wv & 1;
    const int quad = lane >> 4, l16 = lane & 15;

    floatx4 acc[4][4] = {};

    // staging: gload #g covers rows 16g..16g+15 (1 KB); lane l -> row
    // 16g+(l>>2), stored pos l&3, logical chunk (l&3)^(row&3).
    // wave w issues gloads g = 2w, 2w+1 for A and for B.
    const int lrow   = lane >> 2;                      // 0..15 within gload
    const int lchunk = (lane & 3) ^ (lrow & 3);        // logical k-chunk
    const unsigned short* Ag[2];
    const unsigned short* Bg[2];
    int loff[2];
#pragma unroll
    for (int seg = 0; seg < 2; seg++) {
        const int g   = 2 * wv + seg;                  // 0..7
        const int row = 16 * g + lrow;                 // 0..127
        Ag[seg] = A  + (size_t)(m0 + row) * K + lchunk * 8;   // + k0 per iter
        Bg[seg] = Bp + (size_t)(n0 + row) * K + lchunk * 8;
        loff[seg] = 16 * g * 32;                       // wave-uniform
    }

    // read swizzle: logical chunk quad of row (..+l16) is at pos quad^(l16&3)
    const int pk = (quad ^ (l16 & 3)) * 8;

    // prologue: stage k=0..31 into buf 0
#pragma unroll
    for (int seg = 0; seg < 2; seg++) {
        gload16(Ag[seg], &Sh[0][0][loff[seg]]);
        gload16(Bg[seg], &Sh[0][1][loff[seg]]);
    }
    __syncthreads();

    int cur = 0;
    for (int k0 = 0; k0 < K; k0 += 32) {
        // issue next tile's DMA before computing (issue-early)
        if (k0 + 32 < K) {
#pragma unroll
            for (int seg = 0; seg < 2; seg++) {
                gload16(Ag[seg] + k0 + 32, &Sh[cur ^ 1][0][loff[seg]]);
                gload16(Bg[seg] + k0 + 32, &Sh[cur ^ 1][1][loff[seg]]);
            }
        }
        const unsigned short* As = Sh[cur][0];
        const unsigned short* Bs = Sh[cur][1];
        short8 af[4], bf[4];
#pragma unroll
        for (int i = 0; i < 4; i++)
            af[i] = *(const short8*)(As + (wm * 64 + i * 16 + l16) * 32 + pk);
#pragma unroll
        for (int j = 0; j < 4; j++)
            bf[j] = *(const short8*)(Bs + (wn * 64 + j * 16 + l16) * 32 + pk);
#pragma unroll
        for (int i = 0; i < 4; i++)
#pragma unroll
            for (int j = 0; j < 4; j++)
                acc[i][j] = mfma16(af[i], bf[j], acc[i][j]);
        __syncthreads();   // drains vmcnt (next tile landed) + lgkm (reads done)
        cur ^= 1;
    }

#pragma unroll
    for (int i = 0; i < 4; i++)
#pragma unroll
        for (int j = 0; j < 4; j++) {
            const int row = m0 + wm * 64 + i * 16 + quad * 4;
            const int col = n0 + wn * 64 + j * 16 + l16;
#pragma unroll
            for (int r = 0; r < 4; r++) {
                float v = acc[i][j][r];
                if (MODE == 0) {
                    if (z == 0) v *= 0.18033688f;   // 0.125 * log2(e)
                    ((unsigned short*)Cout)[(size_t)z * M * N + (size_t)(row + r) * N + col] = f2b(v);
                } else {
                    size_t idx = (size_t)(row + r) * N + col;
                    ((float*)Cout)[idx] = v + resid[idx];
                }
            }
        }
}

// ---------------------------------------------------------------------------
// K1b: output-projection GEMM + residual — r13-verified: 64x128 tile,
// grid 512, 3 blocks/CU. Bit-exact K-chain. UNCHANGED this round
// (single-variable attribution for the K1 dbuf experiment).
// ---------------------------------------------------------------------------
__launch_bounds__(256, 3)
__global__ void gemm_nt1(const unsigned short* __restrict__ A,
                         const unsigned short* __restrict__ Bw,
                         float* __restrict__ Cout,
                         const float* __restrict__ resid,
                         int M, int N, int K) {
    __shared__ __align__(16) unsigned short As[64 * 64];
    __shared__ __align__(16) unsigned short Bs[128 * 64];

    const int m0 = blockIdx.y * 64, n0 = blockIdx.x * 128;
    const int tid  = threadIdx.x;
    const int lane = tid & 63, wv = tid >> 6;
    const int wm = wv >> 1, wn = wv & 1;
    const int quad = lane >> 4, l16 = lane & 15;

    floatx4 acc[2][4] = {};

    const int r0 = lane >> 3;
    const int jc = ((lane & 7) ^ r0) * 8;
    const unsigned short* Ag[2];
    const unsigned short* Bg[4];
    unsigned short* Asd[2];
    unsigned short* Bsd[4];
#pragma unroll
    for (int seg = 0; seg < 2; seg++) {
        const int row = seg * 32 + wv * 8 + r0;        // 0..63
        Ag[seg]  = A + (size_t)(m0 + row) * K + jc;    // + k0 per iter
        Asd[seg] = As + (seg * 32 + wv * 8) * 64;      // wave-uniform
    }
#pragma unroll
    for (int seg = 0; seg < 4; seg++) {
        const int row = seg * 32 + wv * 8 + r0;        // 0..127
        Bg[seg]  = Bw + (size_t)(n0 + row) * K + jc;
        Bsd[seg] = Bs + (seg * 32 + wv * 8) * 64;
    }

    const int pk0 = (quad ^ (l16 & 7)) * 8;
    const int pk1 = ((4 + quad) ^ (l16 & 7)) * 8;

    for (int k0 = 0; k0 < K; k0 += 64) {
        __syncthreads();
#pragma unroll
        for (int seg = 0; seg < 2; seg++)
            gload16(Ag[seg] + k0, Asd[seg]);
#pragma unroll
        for (int seg = 0; seg < 4; seg++)
            gload16(Bg[seg] + k0, Bsd[seg]);
        __syncthreads();

#pragma unroll
        for (int h = 0; h < 2; h++) {
            const int pk = h ? pk1 : pk0;
            short8 af[2], bf[4];
#pragma unroll
            for (int i = 0; i < 2; i++)
                af[i] = *(const short8*)(As + (wm * 32 + i * 16 + l16) * 64 + pk);
#pragma unroll
            for (int j = 0; j < 4; j++)
                bf[j] = *(const short8*)(Bs + (wn * 64 + j * 16 + l16) * 64 + pk);
#pragma unroll
            for (int i = 0; i < 2; i++)
#pragma unroll
                for (int j = 0; j < 4; j++)
                    acc[i][j] = mfma16(af[i], bf[j], acc[i][j]);
        }
    }

#pragma unroll
    for (int i = 0; i < 2; i++)
#pragma unroll
        for (int j = 0; j < 4; j++) {
            const int row = m0 + wm * 32 + i * 16 + quad * 4;
            const int col = n0 + wn * 64 + j * 16 + l16;
#pragma unroll
            for (int r = 0; r < 4; r++) {
                size_t idx = (size_t)(row + r) * N + col;
                Cout[idx] = acc[i][j][r] + resid[idx];
            }
        }
}

// ---------------------------------------------------------------------------
// K2: FUSED column-softmax denominators + scaled V^T — key-split (64 keys/
// block, grid 1024, 4 blocks/CU) + tile-pair interleave (r11-verified).
// Phase 1: invl[k] = 1/sum_q exp2(s[q,k]) (K-stationary).
// Phase 2: VT[bh][d][k] = V[b][k][h*64+d] * invl[k].
// ---------------------------------------------------------------------------
__launch_bounds__(256, 4)
__global__ void stats_vt_kernel(const unsigned short* __restrict__ Qb,
                                const unsigned short* __restrict__ Kb,
                                const unsigned short* __restrict__ Vb,
                                unsigned short* __restrict__ VT) {
    // two staging tiles; Qs[0] reused as the 64x65 transpose tile in phase 2
    __shared__ __align__(16) unsigned short Qs[2][64 * 66];
    __shared__ float s_inv[64];

    const int id = blockIdx.x;                       // 0..1023
    const int bh = (id & 7) + 8 * ((id >> 3) & 3);   // XCD-grouped
    const int keyblk = id >> 5;                      // 0..31 (64 keys each)
    const int b = bh >> 4, h = bh & 15;
    const int tid = threadIdx.x, lane = tid & 63, w = tid >> 6;   // w = 0..3
    const int quad = lane >> 4, l16 = lane & 15;
    const int keybase = keyblk * 64 + w * 16;        // 16 keys per wave

    // A-frag: K rows (one 16-key tile x 2 dh-halves), held in regs
    short8 ak0, ak1;
    {
        const unsigned short* Krow = Kb + (size_t)(b * kS + keybase + l16) * kD + h * kDh;
        ak0 = *(const short8*)(Krow + quad * 8);
        ak1 = *(const short8*)(Krow + 32 + quad * 8);
    }

    // staging: wave w covers rows w*16 .. w*16+15 (2 segs of 8 rows);
    // lane covers row seg*8 + (lane>>3), logical 16B chunk (lane&7)^r0
    const int r0 = lane >> 3;
    const int jc = ((lane & 7) ^ r0) * 8;
    const unsigned short* Qg[2];
    int loff[2];
#pragma unroll
    for (int seg = 0; seg < 2; seg++) {
        const int row = w * 16 + seg * 8 + r0;              // 0..63
        Qg[seg] = Qb + (size_t)(b * kS + row) * kD + h * kDh + jc;   // + q0*kD per chunk
        loff[seg] = (w * 16 + seg * 8) * 64;                // wave-uniform
    }

    const int pk0 = (quad ^ (l16 & 7)) * 8;
    const int pk1 = ((4 + quad) ^ (l16 & 7)) * 8;

    float lacc[4] = {};

    for (int q0 = 0; q0 < kS; q0 += 128) {
        __syncthreads();   // previous tiles' reads complete before overwrite
#pragma unroll
        for (int seg = 0; seg < 2; seg++) {
            gload16(Qg[seg] + (size_t)q0 * kD,        &Qs[0][loff[seg]]);
            gload16(Qg[seg] + (size_t)(q0 + 64) * kD, &Qs[1][loff[seg]]);
        }
        __syncthreads();   // implicit vmcnt(0): both tiles landed

#pragma unroll
        for (int tb = 0; tb < 2; tb++) {
#pragma unroll
            for (int c = 0; c < 4; c++) {
                const unsigned short* row = &Qs[tb][(c * 16 + l16) * 64];
                short8 bq0 = *(const short8*)(row + pk0);
                short8 bq1 = *(const short8*)(row + pk1);
                floatx4 t = {0.f, 0.f, 0.f, 0.f};
                t = mfma16(ak0, bq0, t);
                t = mfma16(ak1, bq1, t);
#pragma unroll
                for (int r = 0; r < 4; r++)
                    lacc[r] += exp2f(t[r]);
            }
        }
    }

    // reduce across the 16 l16 lanes (q columns) within each quad
#pragma unroll
    for (int off = 1; off <= 8; off <<= 1)
#pragma unroll
        for (int r = 0; r < 4; r++)
            lacc[r] += __shfl_xor(lacc[r], off, 64);

    __syncthreads();   // Qs reads done before tile reuse; also orders s_inv
    if (l16 == 0) {
#pragma unroll
        for (int r = 0; r < 4; r++)
            s_inv[w * 16 + quad * 4 + r] = 1.0f / lacc[r];
    }
    __syncthreads();

    // Phase 2: scaled V^T for this block's 64 keys.
    unsigned short* tile = &Qs[0][0];   // reuse, stride 65 (4160 <= 4224 OK)
    {
        const int kr = tid >> 2, dc = (tid & 3) * 16;
        const float iv = s_inv[kr];
        const unsigned short* src =
            Vb + (size_t)(b * kS + keyblk * 64 + kr) * kD + h * kDh + dc;
        unsigned short vs[16];
        *(uint4*)(vs)     = *(const uint4*)(src);
        *(uint4*)(vs + 8) = *(const uint4*)(src + 8);
#pragma unroll
        for (int i = 0; i < 16; i++)
            tile[kr * 65 + dc + i] = f2b(b2f(vs[i]) * iv);
    }
    __syncthreads();
    {
        const int d = tid >> 2, kc = (tid & 3) * 16;
        unsigned short os[16];
#pragma unroll
        for (int j = 0; j < 16; j++) os[j] = tile[(kc + j) * 65 + d];
        unsigned short* dst =
            VT + (size_t)bh * kDh * kS + (size_t)d * kS + keyblk * 64 + kc;
        *(uint4*)(dst)     = *(uint4*)(os);
        *(uint4*)(dst + 8) = *(uint4*)(os + 8);
    }
}

// ---------------------------------------------------------------------------
// K3: ctx = exp2(S) @ VT^T — tile-pair interleave (verified r9/r11/r13,
// absmax 0.03125). FROZEN: latency floor at 2 waves/SIMD; all further
// levers change accumulation order (fatal, round 4). Same-source noise
// band 61.6-68.3us; do not chase.
// ---------------------------------------------------------------------------
__launch_bounds__(256, 2)
__global__ void ctx_kernel(const unsigned short* __restrict__ Qb,
                           const unsigned short* __restrict__ Kb,
                           const unsigned short* __restrict__ VT,
                           unsigned short* __restrict__ Ctx) {
    // [tile][0] = K tile, [tile][1] = VT tile; 32 KB total.
    __shared__ __align__(16) unsigned short Sh[2][2][64 * 64];

    const int id = blockIdx.x;                       // 0..511
    const int bh = (id & 7) + 8 * ((id >> 3) & 3);   // XCD-grouped
    const int qblk = id >> 5;                        // 0..15
    const int b = bh >> 4, h = bh & 15;
    const int tid = threadIdx.x, lane = tid & 63, w = tid >> 6;   // w = 0..3
    const int l32 = lane & 31, hi = lane >> 5;
    const int qbase = qblk * 128 + w * 32;           // 32 q per wave

    // Q-frags (B-operand of QK^T), 4 dh-ksteps: lane: q=l32, dh=kq*16+hi*8
    short8 aq[4];
    {
        const unsigned short* Qrow =
            Qb + (size_t)(b * kS + qbase + l32) * kD + h * kDh + hi * 8;
#pragma unroll
        for (int kq = 0; kq < 4; kq++)
            aq[kq] = *(const short8*)(Qrow + kq * 16);
    }
    floatx16 acc[2] = {};   // PV acc: d-tiles t=0,1 (rows=q via regs, col=lane&31=d)

    const unsigned short* Kbase = Kb + (size_t)(b * kS) * kD + h * kDh;
    const unsigned short* VTb   = VT + (size_t)bh * kDh * kS;

    // staging: 4 waves cover 64 rows, XOR-chunk source (linear LDS dest)
    const int r0 = lane >> 3;
    const int jc = ((lane & 7) ^ r0) * 8;
    const unsigned short* Kg[2];
    const unsigned short* Vg[2];
    int loff[2];
#pragma unroll
    for (int seg = 0; seg < 2; seg++) {
        const int row = w * 16 + seg * 8 + r0;         // 0..63
        Kg[seg] = Kbase + (size_t)row * kD + jc;       // + k0*kD per chunk
        Vg[seg] = VTb + (size_t)row * kS + jc;         // + k0 per chunk
        loff[seg] = (w * 16 + seg * 8) * 64;           // wave-uniform
    }

    const int x7 = l32 & 7;    // row&7 for the chunk swizzle

    for (int k0 = 0; k0 < kS; k0 += 128) {
        // stage tile k0 into Sh[0], tile k0+64 into Sh[1]
#pragma unroll
        for (int seg = 0; seg < 2; seg++) {
            gload16(Kg[seg] + (size_t)k0 * kD,        &Sh[0][0][loff[seg]]);
            gload16(Vg[seg] + k0,                     &Sh[0][1][loff[seg]]);
            gload16(Kg[seg] + (size_t)(k0 + 64) * kD, &Sh[1][0][loff[seg]]);
            gload16(Vg[seg] + (k0 + 64),              &Sh[1][1][loff[seg]]);
        }
        __syncthreads();   // implicit vmcnt(0): both tiles landed

        // two round-3-verbatim compute bodies, no barrier between ->
        // compiler can interleave tile1's ds_read/QK^T with tile0's
        // exp2/pack/PV. Accumulation order preserved (tb=0 then tb=1).
#pragma unroll
        for (int tb = 0; tb < 2; tb++) {
            const unsigned short* Ks  = Sh[tb][0];
            const unsigned short* VTs = Sh[tb][1];

            // QK^T: sc[s] = K-tile(s) x Q -> D[key][q], col=lane&31=q,
            // key = (r&3) + 8*(r>>2) + 4*hi (+32s)
            floatx16 sc[2];
#pragma unroll
            for (int s = 0; s < 2; s++) {
                const unsigned short* arow = Ks + (s * 32 + l32) * 64;
                floatx16 t = {0.f,0.f,0.f,0.f,0.f,0.f,0.f,0.f,
                              0.f,0.f,0.f,0.f,0.f,0.f,0.f,0.f};
#pragma unroll
                for (int kq = 0; kq < 4; kq++) {
                    short8 af = *(const short8*)(arow + ((2 * kq + hi) ^ x7) * 8);
                    t = mfma32(af, aq[kq], t);
                }
                sc[s] = t;
            }

            // P build fully in-register: exp2 -> truncating bf16 pack ->
            // permlane32_swap. pa[kk] = A-frag (q=l32, keys kk*16+hi*8..+8).
            short8 pa[4];
#pragma unroll
            for (int s = 0; s < 2; s++) {
                float e[16];
#pragma unroll
                for (int r = 0; r < 16; r++) e[r] = exp2f(sc[s][r]);
                unsigned p0 = packbf(e[0],  e[1]),  p1 = packbf(e[2],  e[3]);
                unsigned p2 = packbf(e[4],  e[5]),  p3 = packbf(e[6],  e[7]);
                unsigned p4 = packbf(e[8],  e[9]),  p5 = packbf(e[10], e[11]);
                unsigned p6 = packbf(e[12], e[13]), p7 = packbf(e[14], e[15]);
                asm volatile("v_permlane32_swap_b32 %0, %1" : "+v"(p0), "+v"(p2));
                asm volatile("v_permlane32_swap_b32 %0, %1" : "+v"(p1), "+v"(p3));
                asm volatile("v_permlane32_swap_b32 %0, %1" : "+v"(p4), "+v"(p6));
                asm volatile("v_permlane32_swap_b32 %0, %1" : "+v"(p5), "+v"(p7));
                union { unsigned u[4]; short8 v; } f0, f1;
                f0.u[0] = p0; f0.u[1] = p1; f0.u[2] = p2; f0.u[3] = p3;
                f1.u[0] = p4; f1.u[1] = p5; f1.u[2] = p6; f1.u[3] = p7;
                pa[2 * s]     = f0.v;
                pa[2 * s + 1] = f1.v;
            }

            // PV: acc[t] += P x VT-tile(t) -> D[q][d]
#pragma unroll
            for (int t = 0; t < 2; t++) {
                const unsigned short* brow = VTs + (t * 32 + l32) * 64;
#pragma unroll
                for (int kk = 0; kk < 4; kk++) {
                    short8 bv = *(const short8*)(brow + ((2 * kk + hi) ^ x7) * 8);
                    acc[t] = mfma32(pa[kk], bv, acc[t]);
                }
            }
        }

        __syncthreads();   // all reads done before next stage overwrites
    }

    // D layout: col=lane&31 = d_local (within tile t), row q = (r&3)+8*(r>>2)+4*hi
#pragma unroll
    for (int t = 0; t < 2; t++)
#pragma unroll
        for (int rg = 0; rg < 4; rg++)
#pragma unroll
            for (int j = 0; j < 4; j++) {
                const int q = qbase + rg * 8 + hi * 4 + j;
                const int d = h * kDh + t * 32 + l32;
                Ctx[(size_t)(b * kS + q) * kD + d] = f2b(acc[t][rg * 4 + j]);
            }
}

// ---------------------------------------------------------------------------
// K4: row LayerNorm — wave-per-row, zero barriers (r13-verified).
// ---------------------------------------------------------------------------
__global__ void ln_kernel(const float* __restrict__ R, const float* __restrict__ gamma,
                          const float* __restrict__ beta, float* __restrict__ out) {
    const int tid = threadIdx.x, lane = tid & 63, w = tid >> 6;
    const int row = blockIdx.x * 4 + w;
    const float* Rr = R + (size_t)row * kD;
    float4 v[4];
    float s = 0.f, ss = 0.f;
#pragma unroll
    for (int c = 0; c < 4; c++) {
        v[c] = ((const float4*)Rr)[lane + 64 * c];
        s  += v[c].x + v[c].y + v[c].z + v[c].w;
        ss += v[c].x * v[c].x + v[c].y * v[c].y + v[c].z * v[c].z + v[c].w * v[c].w;
    }
#pragma unroll
    for (int off = 32; off > 0; off >>= 1) {
        s  += __shfl_down(s, off, 64);
        ss += __shfl_down(ss, off, 64);
    }
    const float S1 = __shfl(s, 0, 64);
    const float S2 = __shfl(ss, 0, 64);
    const float mu  = S1 * (1.0f / kD);
    const float inv = rsqrtf(S2 * (1.0f / kD) - mu * mu + 1e-5f);
    float* Or = out + (size_t)row * kD;
#pragma unroll
    for (int c = 0; c < 4; c++) {
        const float4 g  = ((const float4*)gamma)[lane + 64 * c];
        const float4 bb = ((const float4*)beta)[lane + 64 * c];
        float4 o;
        o.x = (v[c].x - mu) * inv * g.x + bb.x;
        o.y = (v[c].y - mu) * inv * g.y + bb.y;
        o.z = (v[c].z - mu) * inv * g.z + bb.z;
        o.w = (v[c].w - mu) * inv * g.w + bb.w;
        ((float4*)Or)[lane + 64 * c] = o;
    }
}

// ---------------------------------------------------------------------------
// Workspace layout (64 MB peak, aliasing is stream-ordered-safe):
//   [0,   8MB)  Xb bf16
//   [8,  16MB)  Wb bf16 wq|wk|wv|wo
//   [16, 40MB)  QKV bf16 Q|K|V  (Q pre-scaled by 0.125*log2e)
//   [40, 48MB)  Ctx bf16
//   [48, 64MB)  VT bf16 [32][64][2048]; ALIASES R (written strictly later)
// ---------------------------------------------------------------------------
extern "C" void kernel_launch(void* const* d_in, const int* in_sizes, int n_in,
                              void* d_out, int out_size, void* d_ws, size_t ws_size,
                              hipStream_t stream) {
    const float* x     = (const float*)d_in[0];
    const float* wq    = (const float*)d_in[1];
    const float* wk    = (const float*)d_in[2];
    const float* wv    = (const float*)d_in[3];
    const float* wo    = (const float*)d_in[4];
    const float* gamma = (const float*)d_in[5];
    const float* beta  = (const float*)d_in[6];
    float* out = (float*)d_out;

    char* ws = (char*)d_ws;
    unsigned short* Xb  = (unsigned short*)(ws);
    unsigned short* Wb  = (unsigned short*)(ws + (8u  << 20));
    unsigned short* QKV = (unsigned short*)(ws + (16u << 20));
    unsigned short* Qb  = QKV;
    unsigned short* Kb  = QKV + (size_t)kBS * kD;
    unsigned short* Vb  = QKV + (size_t)2 * kBS * kD;
    unsigned short* Ctx = (unsigned short*)(ws + (40u << 20));
    unsigned short* VT  = (unsigned short*)(ws + (48u << 20));
    float* R            = (float*)(ws + (48u << 20));  // aliases VT

    convert_kernel<<<2048, 256, 0, stream>>>(x, wq, wk, wv, wo, Xb, Wb);

    gemm_nt<0><<<dim3(kD / 128, kBS / 128, 3), 256, 0, stream>>>(
        Xb, Wb, QKV, nullptr, kBS, kD, kD);

    stats_vt_kernel<<<1024, 256, 0, stream>>>(Qb, Kb, Vb, VT);

    ctx_kernel<<<512, 256, 0, stream>>>(Qb, Kb, VT, Ctx);

    gemm_nt1<<<dim3(kD / 128, kBS / 64, 1), 256, 0, stream>>>(
        Ctx, Wb + (size_t)3 * kD * kD, R, x, kBS, kD, kD);

    ln_kernel<<<kBS / 4, 256, 0, stream>>>(R, gamma, beta, out);
}

// Round 16
// 235.659 us; speedup vs baseline: 1.0051x; 1.0051x over previous
//
#include <hip/hip_runtime.h>
#include <hip/hip_bf16.h>

// Problem constants
constexpr int kB   = 2;
constexpr int kS   = 2048;
constexpr int kD   = 1024;
constexpr int kH   = 16;
constexpr int kDh  = 64;
constexpr int kBS  = kB * kS;          // 4096 rows

typedef __attribute__((ext_vector_type(8))) short short8;   // 8 bf16 = 4 VGPRs
typedef __attribute__((ext_vector_type(4))) float floatx4;  // MFMA acc 16x16
typedef __attribute__((ext_vector_type(16))) float floatx16; // MFMA acc 32x32

__device__ inline unsigned short f2b(float f) {
    __hip_bfloat16 h = __float2bfloat16(f);
    return *reinterpret_cast<unsigned short*>(&h);
}

__device__ inline float b2f(unsigned short u) {
    union { unsigned u; float f; } cv;
    cv.u = (unsigned)u << 16;
    return cv.f;
}

__device__ inline floatx4 mfma16(short8 a, short8 b, floatx4 c) {
    return __builtin_amdgcn_mfma_f32_16x16x32_bf16(a, b, c, 0, 0, 0);
}

__device__ inline floatx16 mfma32(short8 a, short8 b, floatx16 c) {
    return __builtin_amdgcn_mfma_f32_32x32x16_bf16(a, b, c, 0, 0, 0);
}

// truncating pack of two f32 -> one u32 of 2 bf16 (lo = a, hi = b).
// Truncating is part of the round-3 verified arithmetic — do not change
// (absmax 0.03125 depends on reproducing it bit-exactly).
__device__ inline unsigned packbf(float a, float b) {
    union { float f; unsigned u; } x, y;
    x.f = a; y.f = b;
    return (x.u >> 16) | (y.u & 0xffff0000u);
}

// async global->LDS, 16B per lane; LDS dest = wave-uniform base + lane*16
__device__ inline void gload16(const unsigned short* g, unsigned short* l) {
    __builtin_amdgcn_global_load_lds(
        (const __attribute__((address_space(1))) void*)g,
        (__attribute__((address_space(3))) void*)l, 16, 0, 0);
}

// ---------------------------------------------------------------------------
// K0: fp32 -> bf16 conversion of x (4M elems) and the 4 weights (4 x 1M elems)
// 2048 blocks + 4-step grid-stride (guideline 11).
// ---------------------------------------------------------------------------
__global__ void convert_kernel(const float* __restrict__ x,
                               const float* __restrict__ wq, const float* __restrict__ wk,
                               const float* __restrict__ wv, const float* __restrict__ wo,
                               unsigned short* __restrict__ xb, unsigned short* __restrict__ wb) {
#pragma unroll
    for (int it = 0; it < 4; it++) {
        int gid = blockIdx.x * blockDim.x + threadIdx.x + it * (2048 * 256);
        long i4 = (long)gid * 4;
        const float* src;
        unsigned short* dst;
        long off;
        if (i4 < (long)kBS * kD) {
            src = x; dst = xb; off = i4;
        } else {
            long w = i4 - (long)kBS * kD;
            int sel = (int)(w >> 20);
            off = w & 1048575;
            src = (sel == 0) ? wq : (sel == 1) ? wk : (sel == 2) ? wv : wo;
            dst = wb + (long)sel * 1048576;
        }
        float4 v = *(const float4*)(src + off);
        ushort4 o;
        o.x = f2b(v.x); o.y = f2b(v.y); o.z = f2b(v.z); o.w = f2b(v.w);
        *(ushort4*)(dst + off) = o;
    }
}

// ---------------------------------------------------------------------------
// K1: QKV NT GEMM  C[z][M,N] = A[M,K] @ B[z][N,K]^T  (bf16 in, fp32 accum)
// Round 16 resubmit (r15 GPU acquisition timed out; change untested):
// r13-verified BK=64 body (BK=32 dbuf was NEUTRAL in r14 — third null for
// issue-early dbuf on this problem; staging drain is not the stall)
// + NEW coalesced epilogue: old C-write was scalar ushort per element
// (4x32B transactions per store, ~25% write eff on 25MB). Now the k-loop's
// dead staging LDS is reused as a 128x128 bounce tile; lanes re-read
// row-major uint4 -> 256B-contiguous stores per quarter-wave.
// BIT-EXACT: same values, same MFMA chain; only the store path changes.
// z==0 (Q) scaled by 0.125*log2(e) (exp2 domain).
// ---------------------------------------------------------------------------
__launch_bounds__(256, 3)
__global__ void gemm_nt(const unsigned short* __restrict__ A,
                        const unsigned short* __restrict__ Bw,
                        unsigned short* __restrict__ Cout,
                        int M, int N, int K) {
    __shared__ __align__(16) unsigned short Sh[2][128 * 64];   // [0]=As, [1]=Bs
    unsigned short* As = Sh[0];
    unsigned short* Bs = Sh[1];

    const int z  = blockIdx.z;
    const unsigned short* Bp = Bw + (size_t)z * N * K;
    const int m0 = blockIdx.y * 128, n0 = blockIdx.x * 128;
    const int tid  = threadIdx.x;
    const int lane = tid & 63, wv = tid >> 6;
    const int wm = wv >> 1, wn = wv & 1;
    const int quad = lane >> 4, l16 = lane & 15;

    floatx4 acc[4][4] = {};

    const int r0 = lane >> 3;
    const int jc = ((lane & 7) ^ r0) * 8;
    const unsigned short* Ag[4];
    const unsigned short* Bg[4];
    unsigned short* Asd[4];
    unsigned short* Bsd[4];
#pragma unroll
    for (int seg = 0; seg < 4; seg++) {
        const int row = seg * 32 + wv * 8 + r0;        // 0..127
        Ag[seg] = A  + (size_t)(m0 + row) * K + jc;    // + k0 per iter
        Bg[seg] = Bp + (size_t)(n0 + row) * K + jc;
        Asd[seg] = As + (seg * 32 + wv * 8) * 64;      // wave-uniform
        Bsd[seg] = Bs + (seg * 32 + wv * 8) * 64;
    }

    const int pk0 = (quad ^ (l16 & 7)) * 8;
    const int pk1 = ((4 + quad) ^ (l16 & 7)) * 8;

    for (int k0 = 0; k0 < K; k0 += 64) {
        __syncthreads();
#pragma unroll
        for (int seg = 0; seg < 4; seg++) {
            gload16(Ag[seg] + k0, Asd[seg]);
            gload16(Bg[seg] + k0, Bsd[seg]);
        }
        __syncthreads();

#pragma unroll
        for (int h = 0; h < 2; h++) {
            const int pk = h ? pk1 : pk0;
            short8 af[4], bf[4];
#pragma unroll
            for (int i = 0; i < 4; i++)
                af[i] = *(const short8*)(As + (wm * 64 + i * 16 + l16) * 64 + pk);
#pragma unroll
            for (int j = 0; j < 4; j++)
                bf[j] = *(const short8*)(Bs + (wn * 64 + j * 16 + l16) * 64 + pk);
#pragma unroll
            for (int i = 0; i < 4; i++)
#pragma unroll
                for (int j = 0; j < 4; j++)
                    acc[i][j] = mfma16(af[i], bf[j], acc[i][j]);
        }
    }

    // --- coalesced epilogue via LDS bounce (staging bufs are dead) ---
    __syncthreads();   // final tile's ds_reads complete before overwrite
    unsigned short* Cs = &Sh[0][0];   // 2*128*64 = 128*128 ushorts = 32 KB
#pragma unroll
    for (int i = 0; i < 4; i++)
#pragma unroll
        for (int j = 0; j < 4; j++) {
            const int lr0 = wm * 64 + i * 16 + quad * 4;
            const int lc  = wn * 64 + j * 16 + l16;
#pragma unroll
            for (int r = 0; r < 4; r++) {
                float v = acc[i][j][r];
                if (z == 0) v *= 0.18033688f;   // 0.125 * log2(e)
                Cs[(lr0 + r) * 128 + lc] = f2b(v);
            }
        }
    __syncthreads();
    {
        const int srow = tid >> 4;            // 0..15
        const int scol = (tid & 15) * 8;      // ushort offset, 16B chunks
        unsigned short* Cz = Cout + (size_t)z * M * N;
#pragma unroll
        for (int p = 0; p < 8; p++) {
            const int row = p * 16 + srow;    // 0..127
            uint4 vv = *(const uint4*)(Cs + row * 128 + scol);
            *(uint4*)(Cz + (size_t)(m0 + row) * N + n0 + scol) = vv;
        }
    }
}

// ---------------------------------------------------------------------------
// K1b: output-projection GEMM + residual — r13-verified: 64x128 tile,
// grid 512, 3 blocks/CU. Bit-exact K-chain. UNCHANGED (attribution).
// ---------------------------------------------------------------------------
__launch_bounds__(256, 3)
__global__ void gemm_nt1(const unsigned short* __restrict__ A,
                         const unsigned short* __restrict__ Bw,
                         float* __restrict__ Cout,
                         const float* __restrict__ resid,
                         int M, int N, int K) {
    __shared__ __align__(16) unsigned short As[64 * 64];
    __shared__ __align__(16) unsigned short Bs[128 * 64];

    const int m0 = blockIdx.y * 64, n0 = blockIdx.x * 128;
    const int tid  = threadIdx.x;
    const int lane = tid & 63, wv = tid >> 6;
    const int wm = wv >> 1, wn = wv & 1;
    const int quad = lane >> 4, l16 = lane & 15;

    floatx4 acc[2][4] = {};

    const int r0 = lane >> 3;
    const int jc = ((lane & 7) ^ r0) * 8;
    const unsigned short* Ag[2];
    const unsigned short* Bg[4];
    unsigned short* Asd[2];
    unsigned short* Bsd[4];
#pragma unroll
    for (int seg = 0; seg < 2; seg++) {
        const int row = seg * 32 + wv * 8 + r0;        // 0..63
        Ag[seg]  = A + (size_t)(m0 + row) * K + jc;    // + k0 per iter
        Asd[seg] = As + (seg * 32 + wv * 8) * 64;      // wave-uniform
    }
#pragma unroll
    for (int seg = 0; seg < 4; seg++) {
        const int row = seg * 32 + wv * 8 + r0;        // 0..127
        Bg[seg]  = Bw + (size_t)(n0 + row) * K + jc;
        Bsd[seg] = Bs + (seg * 32 + wv * 8) * 64;
    }

    const int pk0 = (quad ^ (l16 & 7)) * 8;
    const int pk1 = ((4 + quad) ^ (l16 & 7)) * 8;

    for (int k0 = 0; k0 < K; k0 += 64) {
        __syncthreads();
#pragma unroll
        for (int seg = 0; seg < 2; seg++)
            gload16(Ag[seg] + k0, Asd[seg]);
#pragma unroll
        for (int seg = 0; seg < 4; seg++)
            gload16(Bg[seg] + k0, Bsd[seg]);
        __syncthreads();

#pragma unroll
        for (int h = 0; h < 2; h++) {
            const int pk = h ? pk1 : pk0;
            short8 af[2], bf[4];
#pragma unroll
            for (int i = 0; i < 2; i++)
                af[i] = *(const short8*)(As + (wm * 32 + i * 16 + l16) * 64 + pk);
#pragma unroll
            for (int j = 0; j < 4; j++)
                bf[j] = *(const short8*)(Bs + (wn * 64 + j * 16 + l16) * 64 + pk);
#pragma unroll
            for (int i = 0; i < 2; i++)
#pragma unroll
                for (int j = 0; j < 4; j++)
                    acc[i][j] = mfma16(af[i], bf[j], acc[i][j]);
        }
    }

#pragma unroll
    for (int i = 0; i < 2; i++)
#pragma unroll
        for (int j = 0; j < 4; j++) {
            const int row = m0 + wm * 32 + i * 16 + quad * 4;
            const int col = n0 + wn * 64 + j * 16 + l16;
#pragma unroll
            for (int r = 0; r < 4; r++) {
                size_t idx = (size_t)(row + r) * N + col;
                Cout[idx] = acc[i][j][r] + resid[idx];
            }
        }
}

// ---------------------------------------------------------------------------
// K2: FUSED column-softmax denominators + scaled V^T — key-split (64 keys/
// block, grid 1024, 4 blocks/CU) + tile-pair interleave (r11-verified).
// Phase 1: invl[k] = 1/sum_q exp2(s[q,k]) (K-stationary).
// Phase 2: VT[bh][d][k] = V[b][k][h*64+d] * invl[k].
// ---------------------------------------------------------------------------
__launch_bounds__(256, 4)
__global__ void stats_vt_kernel(const unsigned short* __restrict__ Qb,
                                const unsigned short* __restrict__ Kb,
                                const unsigned short* __restrict__ Vb,
                                unsigned short* __restrict__ VT) {
    // two staging tiles; Qs[0] reused as the 64x65 transpose tile in phase 2
    __shared__ __align__(16) unsigned short Qs[2][64 * 66];
    __shared__ float s_inv[64];

    const int id = blockIdx.x;                       // 0..1023
    const int bh = (id & 7) + 8 * ((id >> 3) & 3);   // XCD-grouped
    const int keyblk = id >> 5;                      // 0..31 (64 keys each)
    const int b = bh >> 4, h = bh & 15;
    const int tid = threadIdx.x, lane = tid & 63, w = tid >> 6;   // w = 0..3
    const int quad = lane >> 4, l16 = lane & 15;
    const int keybase = keyblk * 64 + w * 16;        // 16 keys per wave

    // A-frag: K rows (one 16-key tile x 2 dh-halves), held in regs
    short8 ak0, ak1;
    {
        const unsigned short* Krow = Kb + (size_t)(b * kS + keybase + l16) * kD + h * kDh;
        ak0 = *(const short8*)(Krow + quad * 8);
        ak1 = *(const short8*)(Krow + 32 + quad * 8);
    }

    // staging: wave w covers rows w*16 .. w*16+15 (2 segs of 8 rows);
    // lane covers row seg*8 + (lane>>3), logical 16B chunk (lane&7)^r0
    const int r0 = lane >> 3;
    const int jc = ((lane & 7) ^ r0) * 8;
    const unsigned short* Qg[2];
    int loff[2];
#pragma unroll
    for (int seg = 0; seg < 2; seg++) {
        const int row = w * 16 + seg * 8 + r0;              // 0..63
        Qg[seg] = Qb + (size_t)(b * kS + row) * kD + h * kDh + jc;   // + q0*kD per chunk
        loff[seg] = (w * 16 + seg * 8) * 64;                // wave-uniform
    }

    const int pk0 = (quad ^ (l16 & 7)) * 8;
    const int pk1 = ((4 + quad) ^ (l16 & 7)) * 8;

    float lacc[4] = {};

    for (int q0 = 0; q0 < kS; q0 += 128) {
        __syncthreads();   // previous tiles' reads complete before overwrite
#pragma unroll
        for (int seg = 0; seg < 2; seg++) {
            gload16(Qg[seg] + (size_t)q0 * kD,        &Qs[0][loff[seg]]);
            gload16(Qg[seg] + (size_t)(q0 + 64) * kD, &Qs[1][loff[seg]]);
        }
        __syncthreads();   // implicit vmcnt(0): both tiles landed

#pragma unroll
        for (int tb = 0; tb < 2; tb++) {
#pragma unroll
            for (int c = 0; c < 4; c++) {
                const unsigned short* row = &Qs[tb][(c * 16 + l16) * 64];
                short8 bq0 = *(const short8*)(row + pk0);
                short8 bq1 = *(const short8*)(row + pk1);
                floatx4 t = {0.f, 0.f, 0.f, 0.f};
                t = mfma16(ak0, bq0, t);
                t = mfma16(ak1, bq1, t);
#pragma unroll
                for (int r = 0; r < 4; r++)
                    lacc[r] += exp2f(t[r]);
            }
        }
    }

    // reduce across the 16 l16 lanes (q columns) within each quad
#pragma unroll
    for (int off = 1; off <= 8; off <<= 1)
#pragma unroll
        for (int r = 0; r < 4; r++)
            lacc[r] += __shfl_xor(lacc[r], off, 64);

    __syncthreads();   // Qs reads done before tile reuse; also orders s_inv
    if (l16 == 0) {
#pragma unroll
        for (int r = 0; r < 4; r++)
            s_inv[w * 16 + quad * 4 + r] = 1.0f / lacc[r];
    }
    __syncthreads();

    // Phase 2: scaled V^T for this block's 64 keys.
    unsigned short* tile = &Qs[0][0];   // reuse, stride 65 (4160 <= 4224 OK)
    {
        const int kr = tid >> 2, dc = (tid & 3) * 16;
        const float iv = s_inv[kr];
        const unsigned short* src =
            Vb + (size_t)(b * kS + keyblk * 64 + kr) * kD + h * kDh + dc;
        unsigned short vs[16];
        *(uint4*)(vs)     = *(const uint4*)(src);
        *(uint4*)(vs + 8) = *(const uint4*)(src + 8);
#pragma unroll
        for (int i = 0; i < 16; i++)
            tile[kr * 65 + dc + i] = f2b(b2f(vs[i]) * iv);
    }
    __syncthreads();
    {
        const int d = tid >> 2, kc = (tid & 3) * 16;
        unsigned short os[16];
#pragma unroll
        for (int j = 0; j < 16; j++) os[j] = tile[(kc + j) * 65 + d];
        unsigned short* dst =
            VT + (size_t)bh * kDh * kS + (size_t)d * kS + keyblk * 64 + kc;
        *(uint4*)(dst)     = *(uint4*)(os);
        *(uint4*)(dst + 8) = *(uint4*)(os + 8);
    }
}

// ---------------------------------------------------------------------------
// K3: ctx = exp2(S) @ VT^T — tile-pair interleave (verified r9/r11/r13,
// absmax 0.03125). FROZEN: latency floor at 2 waves/SIMD; all further
// levers change accumulation order (fatal, round 4). Same-source noise
// band 61.6-68.3us; do not chase.
// ---------------------------------------------------------------------------
__launch_bounds__(256, 2)
__global__ void ctx_kernel(const unsigned short* __restrict__ Qb,
                           const unsigned short* __restrict__ Kb,
                           const unsigned short* __restrict__ VT,
                           unsigned short* __restrict__ Ctx) {
    // [tile][0] = K tile, [tile][1] = VT tile; 32 KB total.
    __shared__ __align__(16) unsigned short Sh[2][2][64 * 64];

    const int id = blockIdx.x;                       // 0..511
    const int bh = (id & 7) + 8 * ((id >> 3) & 3);   // XCD-grouped
    const int qblk = id >> 5;                        // 0..15
    const int b = bh >> 4, h = bh & 15;
    const int tid = threadIdx.x, lane = tid & 63, w = tid >> 6;   // w = 0..3
    const int l32 = lane & 31, hi = lane >> 5;
    const int qbase = qblk * 128 + w * 32;           // 32 q per wave

    // Q-frags (B-operand of QK^T), 4 dh-ksteps: lane: q=l32, dh=kq*16+hi*8
    short8 aq[4];
    {
        const unsigned short* Qrow =
            Qb + (size_t)(b * kS + qbase + l32) * kD + h * kDh + hi * 8;
#pragma unroll
        for (int kq = 0; kq < 4; kq++)
            aq[kq] = *(const short8*)(Qrow + kq * 16);
    }
    floatx16 acc[2] = {};   // PV acc: d-tiles t=0,1 (rows=q via regs, col=lane&31=d)

    const unsigned short* Kbase = Kb + (size_t)(b * kS) * kD + h * kDh;
    const unsigned short* VTb   = VT + (size_t)bh * kDh * kS;

    // staging: 4 waves cover 64 rows, XOR-chunk source (linear LDS dest)
    const int r0 = lane >> 3;
    const int jc = ((lane & 7) ^ r0) * 8;
    const unsigned short* Kg[2];
    const unsigned short* Vg[2];
    int loff[2];
#pragma unroll
    for (int seg = 0; seg < 2; seg++) {
        const int row = w * 16 + seg * 8 + r0;         // 0..63
        Kg[seg] = Kbase + (size_t)row * kD + jc;       // + k0*kD per chunk
        Vg[seg] = VTb + (size_t)row * kS + jc;         // + k0 per chunk
        loff[seg] = (w * 16 + seg * 8) * 64;           // wave-uniform
    }

    const int x7 = l32 & 7;    // row&7 for the chunk swizzle

    for (int k0 = 0; k0 < kS; k0 += 128) {
        // stage tile k0 into Sh[0], tile k0+64 into Sh[1]
#pragma unroll
        for (int seg = 0; seg < 2; seg++) {
            gload16(Kg[seg] + (size_t)k0 * kD,        &Sh[0][0][loff[seg]]);
            gload16(Vg[seg] + k0,                     &Sh[0][1][loff[seg]]);
            gload16(Kg[seg] + (size_t)(k0 + 64) * kD, &Sh[1][0][loff[seg]]);
            gload16(Vg[seg] + (k0 + 64),              &Sh[1][1][loff[seg]]);
        }
        __syncthreads();   // implicit vmcnt(0): both tiles landed

        // two round-3-verbatim compute bodies, no barrier between ->
        // compiler can interleave tile1's ds_read/QK^T with tile0's
        // exp2/pack/PV. Accumulation order preserved (tb=0 then tb=1).
#pragma unroll
        for (int tb = 0; tb < 2; tb++) {
            const unsigned short* Ks  = Sh[tb][0];
            const unsigned short* VTs = Sh[tb][1];

            // QK^T: sc[s] = K-tile(s) x Q -> D[key][q], col=lane&31=q,
            // key = (r&3) + 8*(r>>2) + 4*hi (+32s)
            floatx16 sc[2];
#pragma unroll
            for (int s = 0; s < 2; s++) {
                const unsigned short* arow = Ks + (s * 32 + l32) * 64;
                floatx16 t = {0.f,0.f,0.f,0.f,0.f,0.f,0.f,0.f,
                              0.f,0.f,0.f,0.f,0.f,0.f,0.f,0.f};
#pragma unroll
                for (int kq = 0; kq < 4; kq++) {
                    short8 af = *(const short8*)(arow + ((2 * kq + hi) ^ x7) * 8);
                    t = mfma32(af, aq[kq], t);
                }
                sc[s] = t;
            }

            // P build fully in-register: exp2 -> truncating bf16 pack ->
            // permlane32_swap. pa[kk] = A-frag (q=l32, keys kk*16+hi*8..+8).
            short8 pa[4];
#pragma unroll
            for (int s = 0; s < 2; s++) {
                float e[16];
#pragma unroll
                for (int r = 0; r < 16; r++) e[r] = exp2f(sc[s][r]);
                unsigned p0 = packbf(e[0],  e[1]),  p1 = packbf(e[2],  e[3]);
                unsigned p2 = packbf(e[4],  e[5]),  p3 = packbf(e[6],  e[7]);
                unsigned p4 = packbf(e[8],  e[9]),  p5 = packbf(e[10], e[11]);
                unsigned p6 = packbf(e[12], e[13]), p7 = packbf(e[14], e[15]);
                asm volatile("v_permlane32_swap_b32 %0, %1" : "+v"(p0), "+v"(p2));
                asm volatile("v_permlane32_swap_b32 %0, %1" : "+v"(p1), "+v"(p3));
                asm volatile("v_permlane32_swap_b32 %0, %1" : "+v"(p4), "+v"(p6));
                asm volatile("v_permlane32_swap_b32 %0, %1" : "+v"(p5), "+v"(p7));
                union { unsigned u[4]; short8 v; } f0, f1;
                f0.u[0] = p0; f0.u[1] = p1; f0.u[2] = p2; f0.u[3] = p3;
                f1.u[0] = p4; f1.u[1] = p5; f1.u[2] = p6; f1.u[3] = p7;
                pa[2 * s]     = f0.v;
                pa[2 * s + 1] = f1.v;
            }

            // PV: acc[t] += P x VT-tile(t) -> D[q][d]
#pragma unroll
            for (int t = 0; t < 2; t++) {
                const unsigned short* brow = VTs + (t * 32 + l32) * 64;
#pragma unroll
                for (int kk = 0; kk < 4; kk++) {
                    short8 bv = *(const short8*)(brow + ((2 * kk + hi) ^ x7) * 8);
                    acc[t] = mfma32(pa[kk], bv, acc[t]);
                }
            }
        }

        __syncthreads();   // all reads done before next stage overwrites
    }

    // D layout: col=lane&31 = d_local (within tile t), row q = (r&3)+8*(r>>2)+4*hi
#pragma unroll
    for (int t = 0; t < 2; t++)
#pragma unroll
        for (int rg = 0; rg < 4; rg++)
#pragma unroll
            for (int j = 0; j < 4; j++) {
                const int q = qbase + rg * 8 + hi * 4 + j;
                const int d = h * kDh + t * 32 + l32;
                Ctx[(size_t)(b * kS + q) * kD + d] = f2b(acc[t][rg * 4 + j]);
            }
}

// ---------------------------------------------------------------------------
// K4: row LayerNorm — wave-per-row, zero barriers (r13-verified).
// ---------------------------------------------------------------------------
__global__ void ln_kernel(const float* __restrict__ R, const float* __restrict__ gamma,
                          const float* __restrict__ beta, float* __restrict__ out) {
    const int tid = threadIdx.x, lane = tid & 63, w = tid >> 6;
    const int row = blockIdx.x * 4 + w;
    const float* Rr = R + (size_t)row * kD;
    float4 v[4];
    float s = 0.f, ss = 0.f;
#pragma unroll
    for (int c = 0; c < 4; c++) {
        v[c] = ((const float4*)Rr)[lane + 64 * c];
        s  += v[c].x + v[c].y + v[c].z + v[c].w;
        ss += v[c].x * v[c].x + v[c].y * v[c].y + v[c].z * v[c].z + v[c].w * v[c].w;
    }
#pragma unroll
    for (int off = 32; off > 0; off >>= 1) {
        s  += __shfl_down(s, off, 64);
        ss += __shfl_down(ss, off, 64);
    }
    const float S1 = __shfl(s, 0, 64);
    const float S2 = __shfl(ss, 0, 64);
    const float mu  = S1 * (1.0f / kD);
    const float inv = rsqrtf(S2 * (1.0f / kD) - mu * mu + 1e-5f);
    float* Or = out + (size_t)row * kD;
#pragma unroll
    for (int c = 0; c < 4; c++) {
        const float4 g  = ((const float4*)gamma)[lane + 64 * c];
        const float4 bb = ((const float4*)beta)[lane + 64 * c];
        float4 o;
        o.x = (v[c].x - mu) * inv * g.x + bb.x;
        o.y = (v[c].y - mu) * inv * g.y + bb.y;
        o.z = (v[c].z - mu) * inv * g.z + bb.z;
        o.w = (v[c].w - mu) * inv * g.w + bb.w;
        ((float4*)Or)[lane + 64 * c] = o;
    }
}

// ---------------------------------------------------------------------------
// Workspace layout (64 MB peak, aliasing is stream-ordered-safe):
//   [0,   8MB)  Xb bf16
//   [8,  16MB)  Wb bf16 wq|wk|wv|wo
//   [16, 40MB)  QKV bf16 Q|K|V  (Q pre-scaled by 0.125*log2e)
//   [40, 48MB)  Ctx bf16
//   [48, 64MB)  VT bf16 [32][64][2048]; ALIASES R (written strictly later)
// ---------------------------------------------------------------------------
extern "C" void kernel_launch(void* const* d_in, const int* in_sizes, int n_in,
                              void* d_out, int out_size, void* d_ws, size_t ws_size,
                              hipStream_t stream) {
    const float* x     = (const float*)d_in[0];
    const float* wq    = (const float*)d_in[1];
    const float* wk    = (const float*)d_in[2];
    const float* wv    = (const float*)d_in[3];
    const float* wo    = (const float*)d_in[4];
    const float* gamma = (const float*)d_in[5];
    const float* beta  = (const float*)d_in[6];
    float* out = (float*)d_out;

    char* ws = (char*)d_ws;
    unsigned short* Xb  = (unsigned short*)(ws);
    unsigned short* Wb  = (unsigned short*)(ws + (8u  << 20));
    unsigned short* QKV = (unsigned short*)(ws + (16u << 20));
    unsigned short* Qb  = QKV;
    unsigned short* Kb  = QKV + (size_t)kBS * kD;
    unsigned short* Vb  = QKV + (size_t)2 * kBS * kD;
    unsigned short* Ctx = (unsigned short*)(ws + (40u << 20));
    unsigned short* VT  = (unsigned short*)(ws + (48u << 20));
    float* R            = (float*)(ws + (48u << 20));  // aliases VT

    convert_kernel<<<2048, 256, 0, stream>>>(x, wq, wk, wv, wo, Xb, Wb);

    gemm_nt<<<dim3(kD / 128, kBS / 128, 3), 256, 0, stream>>>(
        Xb, Wb, QKV, kBS, kD, kD);

    stats_vt_kernel<<<1024, 256, 0, stream>>>(Qb, Kb, Vb, VT);

    ctx_kernel<<<512, 256, 0, stream>>>(Qb, Kb, VT, Ctx);

    gemm_nt1<<<dim3(kD / 128, kBS / 64, 1), 256, 0, stream>>>(
        Ctx, Wb + (size_t)3 * kD * kD, R, x, kBS, kD, kD);

    ln_kernel<<<kBS / 4, 256, 0, stream>>>(R, gamma, beta, out);
}